// Round 22
// baseline (228.921 us; speedup 1.0000x reference)
//
#include <hip/hip_runtime.h>

// ---------------------------------------------------------------------------
// Swin-3D shifted window attention, MI355X (gfx950)
// R22: R21 (115.0us) + bias table stored as f32 (21.3MB in ws): kills the
//      8 shift/mask VALU ops per (ch,j) (728/wave) and feeds the C-init
//      directly from the prefetched load. Doubles the bias prefetch regs
//      (56->112) — under (2,2)'s 256 budget this forces the allocator past
//      the 128 clamp (diagnostic: VGPR ~180 expected; if 128/spill, clamp
//      is absolute -> revert, plateau). Everything else identical to R21.
// ---------------------------------------------------------------------------

#define DIMC   128
#define HEADS  4
#define HD     32
#define VOL    392
#define VPAD   416
#define TQ     400
#define TK     416
#define SCALE2 0.25503490443f          // (1/sqrt(32)) * log2(e)
#define LOG2E  1.4426950408889634f
#define MASK2  144.26950408889634f     // 100 * log2(e)

typedef __bf16 bf16;
typedef __attribute__((ext_vector_type(8))) __bf16 bf16x8;
typedef __attribute__((ext_vector_type(4))) __bf16 bf16x4;
typedef __attribute__((ext_vector_type(2))) __bf16 bf16x2;
typedef __attribute__((ext_vector_type(4))) float  f32x4;

// LDS layout (bf16 elements): R0 = K (Q transiently), R1 = V^T
#define OFF_VT  (392*32)
#define VTCOLS  416
#define LDS_ELEMS (392*32 + 32*VTCOLS)       // 25856 elems = 51712 B
#define AW_BYTES  (256ull * VPAD * DIMC * 2ull)          // 27.26 MB
#define TBLF_BYTES (8ull * HEADS * TQ * TK * 4ull)       // 21.3 MB

static __device__ inline bf16x8 pack8(float4 a, float4 b) {
    bf16x8 r;
    r[0] = (bf16)a.x; r[1] = (bf16)a.y; r[2] = (bf16)a.z; r[3] = (bf16)a.w;
    r[4] = (bf16)b.x; r[5] = (bf16)b.y; r[6] = (bf16)b.z; r[7] = (bf16)b.w;
    return r;
}
static __device__ inline bf16x8 zero8() {
    bf16x8 z;
#pragma unroll
    for (int i = 0; i < 8; ++i) z[i] = (bf16)0.0f;
    return z;
}
static __device__ inline bf16x8 ones8() {
    bf16x8 z;
#pragma unroll
    for (int i = 0; i < 8; ++i) z[i] = (bf16)1.0f;
    return z;
}
static __device__ inline int swz4(int row) { return ((row >> 1) ^ (row >> 3)) & 3; }

static __device__ inline unsigned pkbf(float a, float b) {
    bf16x2 t; t[0] = (bf16)a; t[1] = (bf16)b;
    return __builtin_bit_cast(unsigned, t);
}

#if defined(__has_builtin)
#if __has_builtin(__builtin_amdgcn_exp2f)
#define HAS_EXP2 1
#endif
#endif
static __device__ inline float exp2_hw(float x) {
#ifdef HAS_EXP2
    return __builtin_amdgcn_exp2f(x);
#else
    float r; asm volatile("v_exp_f32 %0, %1\n\ts_nop 0" : "=v"(r) : "v"(x)); return r;
#endif
}

// ---------------------------------------------------------------------------
// bias+mask table (f32, pre-scaled by log2e) + wproj f32->bf16 (merged)
// ---------------------------------------------------------------------------
__global__ __launch_bounds__(256) void gen_table(const float* __restrict__ btab,
                                                 float* __restrict__ tbl,
                                                 const float* __restrict__ wproj,
                                                 bf16* __restrict__ wpb) {
    const int idx = blockIdx.x * 256 + threadIdx.x;
    if (idx < DIMC * DIMC / 4) {
        const int i = idx * 4;
        float4 u = *(const float4*)(wproj + i);
        bf16x4 o; o[0] = (bf16)u.x; o[1] = (bf16)u.y; o[2] = (bf16)u.z; o[3] = (bf16)u.w;
        *(bf16x4*)(wpb + i) = o;
    }
    const int total = 8 * HEADS * TQ * (TK / 4);
    if (idx >= total) return;
    const int k4  = (idx % (TK / 4)) * 4;
    const int q   = (idx / (TK / 4)) % TQ;
    const int h   = (idx / ((TK / 4) * TQ)) & 3;
    const int pat = idx / ((TK / 4) * TQ * HEADS);
    const int tb = (pat >> 2) & 1, hb = (pat >> 1) & 1, wb = pat & 1;

    int qt = 0, qh = 0, qw = 0, lq = 0;
    if (q < VOL) {
        qt = q / 49; const int qr = q - qt * 49; qh = qr / 7; qw = qr - qh * 7;
        lq = (tb ? (qt < 4 ? 1 : 2) : 0) * 9 + (hb ? (qh < 4 ? 1 : 2) : 0) * 3 +
             (wb ? (qw < 4 ? 1 : 2) : 0);
    }
    float4 out;
    float* op = &out.x;
#pragma unroll
    for (int j = 0; j < 4; ++j) {
        const int k = k4 + j;
        float v;
        if (k >= VOL)      v = -30000.0f;
        else if (q >= VOL) v = 0.0f;
        else {
            const int kt = k / 49; const int kr = k - kt * 49;
            const int kh = kr / 7; const int kw = kr - kh * 7;
            const int rel = ((qt - kt + 7) * 13 + (qh - kh + 6)) * 13 + (qw - kw + 6);
            v = btab[rel * HEADS + h] * LOG2E;
            const int lk = (tb ? (kt < 4 ? 1 : 2) : 0) * 9 +
                           (hb ? (kh < 4 ? 1 : 2) : 0) * 3 +
                           (wb ? (kw < 4 ? 1 : 2) : 0);
            if (lq != lk) v -= MASK2;
        }
        op[j] = v;
    }
    *(float4*)&tbl[((size_t)(pat * HEADS + h) * TQ + q) * TK + k4] = out;
}

// ---------------------------------------------------------------------------
// Kernel A: per (window,head), 256 threads / 4 waves, static 51.7KB LDS.
// ---------------------------------------------------------------------------
#define NJ 7   // q-tiles per wave: wave wv owns mt = wv + 4j

__global__ __attribute__((amdgpu_flat_work_group_size(256, 256),
                          amdgpu_waves_per_eu(2, 2)))
void swin_attn(
    const float* __restrict__ x, const float* __restrict__ wqkv,
    const float* __restrict__ bqkv, const float* __restrict__ tbl,
    bf16* __restrict__ aw)
{
    __shared__ __align__(16) bf16 lds[LDS_ELEMS];

    // XCD-aware mapping: 4 heads of a window -> same XCD (bid%8)
    const int bid  = blockIdx.x;
    const int xcd  = bid & 7;
    const int tt   = bid >> 3;             // 0..127
    const int win  = xcd * 32 + (tt >> 2); // 0..255
    const int head = tt & 3;
    const int b    = win >> 7;
    const int wrem = win & 127;
    const int it   = wrem >> 6;
    const int ih   = (wrem >> 3) & 7;
    const int iw   = wrem & 7;
    const int pat  = ((it == 1) ? 4 : 0) | ((ih == 7) ? 2 : 0) | ((iw == 7) ? 1 : 0);

    const int tid  = threadIdx.x;
    const int lane = tid & 63;
    const int wv   = tid >> 6;             // wave 0..3
    const int l16  = lane & 15;
    const int lg   = lane >> 4;

    const float* tblh = tbl + (size_t)(pat * HEADS + head) * (TQ * TK);

    // ---- hoisted W fragments: o = g*2+h2, g: 0=Q 1=K 2=V ----
    bf16x8 wfr[6][4];
    float  bcol[4];
#pragma unroll
    for (int o = 0; o < 6; ++o) {
        const int g = o >> 1, h2 = o & 1;
        const int wrow = g * DIMC + head * HD + h2 * 16 + l16;
        const float* wp = wqkv + (size_t)wrow * DIMC + 8 * lg;
#pragma unroll
        for (int ks = 0; ks < 4; ++ks)
            wfr[o][ks] = pack8(*(const float4*)(wp + ks * 32),
                               *(const float4*)(wp + ks * 32 + 4));
        if (o < 4) bcol[o] = bqkv[wrow];
    }
    float bvr[2][4];
#pragma unroll
    for (int h2 = 0; h2 < 2; ++h2)
#pragma unroll
        for (int r = 0; r < 4; ++r)
            bvr[h2][r] = bqkv[2 * DIMC + head * HD + h2 * 16 + lg * 4 + r];

    bf16x8 qf[NJ];                 // per-wave Q fragments (STATIC indexing)
#pragma unroll
    for (int j = 0; j < NJ; ++j) qf[j] = zero8();

    // ------- phase 1 (j unrolled, x loads double-buffered one tile ahead) --
    float4 xr0[8], xr1[8];
    bool   ok0 = false, ok1 = false;

#define P1_LOAD(MT, XR, OK)                                                   \
    {                                                                         \
        const int mt_ = (MT);                                                 \
        const int tv_ = mt_ * 16 + l16;                                       \
        OK = (mt_ < 26) && (tv_ < VOL);                                       \
        if (OK) {                                                             \
            const int lt_ = tv_ / 49, rr_ = tv_ - lt_ * 49;                   \
            const int lh_ = rr_ / 7, lw_ = rr_ - lh_ * 7;                     \
            const int t0_ = (it * 8 + lt_ + 4) & 15;                          \
            int h0_ = ih * 7 + lh_ + 3; if (h0_ >= 56) h0_ -= 56;             \
            int w0_ = iw * 7 + lw_ + 3; if (w0_ >= 56) w0_ -= 56;             \
            const float* xp_ = x + (size_t)(((b * 16 + t0_) * 56 + h0_) * 56 + w0_) * DIMC + 8 * lg; \
            _Pragma("unroll")                                                 \
            for (int u = 0; u < 8; ++u)                                       \
                XR[u] = *(const float4*)(xp_ + (u >> 1) * 32 + (u & 1) * 4);  \
        }                                                                     \
    }
#define P1_BODY(J, XR, OK)                                                    \
    {                                                                         \
        const int mt = wv + 4 * (J);                                          \
        if (mt < 26) {                                                        \
            const int tv = mt * 16 + l16;                                     \
            bf16x8 af[4];                                                     \
            _Pragma("unroll")                                                 \
            for (int ks = 0; ks < 4; ++ks)                                    \
                af[ks] = OK ? pack8(XR[2 * ks], XR[2 * ks + 1]) : zero8();    \
            _Pragma("unroll")                                                 \
            for (int o = 0; o < 2; ++o) {                                     \
                f32x4 acc = {0.f, 0.f, 0.f, 0.f};                             \
                _Pragma("unroll")                                             \
                for (int ks = 0; ks < 4; ++ks)                                \
                    acc = __builtin_amdgcn_mfma_f32_16x16x32_bf16(af[ks], wfr[o][ks], acc, 0, 0, 0); \
                const int cb = (o & 1) * 16 + l16;                            \
                _Pragma("unroll")                                             \
                for (int r = 0; r < 4; ++r) {                                 \
                    const int row = mt * 16 + lg * 4 + r;                     \
                    if (row < VOL)                                            \
                        lds[row * 32 + (cb ^ (swz4(row) << 3))] = (bf16)((acc[r] + bcol[o]) * SCALE2); \
                }                                                             \
            }                                                                 \
            if (mt < 25) {                                                    \
                const int qr = (tv < VOL) ? tv : (VOL - 1);                   \
                qf[(J)] = *(const bf16x8*)&lds[qr * 32 + ((lg * 8) ^ (swz4(qr) << 3))]; \
            }                                                                 \
            _Pragma("unroll")                                                 \
            for (int o = 2; o < 4; ++o) {                                     \
                f32x4 acc = {0.f, 0.f, 0.f, 0.f};                             \
                _Pragma("unroll")                                             \
                for (int ks = 0; ks < 4; ++ks)                                \
                    acc = __builtin_amdgcn_mfma_f32_16x16x32_bf16(af[ks], wfr[o][ks], acc, 0, 0, 0); \
                const int cb = (o & 1) * 16 + l16;                            \
                _Pragma("unroll")                                             \
                for (int r = 0; r < 4; ++r) {                                 \
                    const int row = mt * 16 + lg * 4 + r;                     \
                    if (row < VOL)                                            \
                        lds[row * 32 + (cb ^ (swz4(row) << 3))] = (bf16)(acc[r] + bcol[o]); \
                }                                                             \
            }                                                                 \
            _Pragma("unroll")                                                 \
            for (int h2 = 0; h2 < 2; ++h2) {                                  \
                f32x4 acc = {0.f, 0.f, 0.f, 0.f};                             \
                _Pragma("unroll")                                             \
                for (int ks = 0; ks < 4; ++ks)                                \
                    acc = __builtin_amdgcn_mfma_f32_16x16x32_bf16(wfr[4 + h2][ks], af[ks], acc, 0, 0, 0); \
                _Pragma("unroll")                                             \
                for (int r = 0; r < 4; ++r) {                                 \
                    const int n = h2 * 16 + lg * 4 + r;                       \
                    lds[OFF_VT + n * VTCOLS + (tv ^ (swz4(n) << 3))] = (bf16)(acc[r] + bvr[h2][r]); \
                }                                                             \
            }                                                                 \
        }                                                                     \
    }

    P1_LOAD(wv, xr0, ok0)
    P1_LOAD(wv + 4, xr1, ok1)
    P1_BODY(0, xr0, ok0)
    P1_LOAD(wv + 8, xr0, ok0)
    P1_BODY(1, xr1, ok1)
    P1_LOAD(wv + 12, xr1, ok1)
    P1_BODY(2, xr0, ok0)
    P1_LOAD(wv + 16, xr0, ok0)
    P1_BODY(3, xr1, ok1)
    P1_LOAD(wv + 20, xr1, ok1)
    P1_BODY(4, xr0, ok0)
    P1_LOAD(wv + 24, xr0, ok0)
    P1_BODY(5, xr1, ok1)
    P1_BODY(6, xr0, ok0)
#undef P1_LOAD
#undef P1_BODY
    __syncthreads();

    // ---------------- phase 2: ch-outer / q-inner, no-max softmax --------
    // Interleaved S^T tiles: tile A keys = 32ch+{0-3,8-11,16-19,24-27},
    // tile B = +4. Lane (l16,lg): sA[r]=P(key 32ch+8lg+r), sB[r]=+4 -> PV
    // B-frag directly. K reads for keys>=392 overrun into initialized V^T.
    // Denominator on the MFMA pipe: sumv[j] = mfma(ones, P, sumv[j]).
    // Bias rows (f32, no unpack) and K/V LDS frags double-buffered 1 ahead.
    {
        const int c = l16 & 3, d = l16 >> 2;
        const int rowA  = c + 8 * d;
        const int swzA  = (c >> 1) ^ d;
        const int swzB  = (2 + (c >> 1)) ^ d;
        const int kbA   = rowA * 32       + ((lg * 8) ^ (swzA << 3));
        const int kbB   = (rowA + 4) * 32 + ((lg * 8) ^ (swzB << 3));
        const int vb0   = OFF_VT + l16 * VTCOLS        + ((lg * 8) ^ (swz4(l16) << 3));
        const int vb1   = OFF_VT + (16 + l16) * VTCOLS + ((lg * 8) ^ (swz4(16 + l16) << 3));
        const bf16x8 onesf = ones8();

        int    tbOff[NJ];              // 32-bit byte offsets into tblh (f32)
        f32x4  o0[NJ], o1[NJ], sumv[NJ];
#pragma unroll
        for (int j = 0; j < NJ; ++j) {
            const int qtok = (wv + 4 * j) * 16 + l16;
            const int qc   = (qtok < TQ) ? qtok : (TQ - 1);
            tbOff[j] = (qc * TK + 8 * lg) * 4;
            o0[j]   = f32x4{0.f, 0.f, 0.f, 0.f};
            o1[j]   = f32x4{0.f, 0.f, 0.f, 0.f};
            sumv[j] = f32x4{0.f, 0.f, 0.f, 0.f};
        }

        f32x4 bufA[NJ][2], bufB[NJ][2];
        bf16x8 kA0, kB0, v00, v10, kA1, kB1, v01, v11;

#define CH_PREB(CH, DST)                                                      \
        {                                                                     \
            const int chp_ = (CH) < 12 ? (CH) : 12;                           \
            _Pragma("unroll")                                                 \
            for (int j = 0; j < NJ; ++j) {                                    \
                DST[j][0] = *(const f32x4*)((const char*)tblh + tbOff[j] + chp_ * 128); \
                DST[j][1] = *(const f32x4*)((const char*)tblh + tbOff[j] + chp_ * 128 + 16); \
            }                                                                 \
        }
#define CH_PREF(CH, KA, KB, V0, V1)                                           \
        {                                                                     \
            const int chf_ = (CH) < 12 ? (CH) : 12;                           \
            KA = *(const bf16x8*)&lds[kbA + chf_ * 1024];                     \
            KB = *(const bf16x8*)&lds[kbB + chf_ * 1024];                     \
            V0 = *(const bf16x8*)&lds[vb0 + chf_ * 32];                       \
            V1 = *(const bf16x8*)&lds[vb1 + chf_ * 32];                       \
        }
#define CH_BODY(CUR, KA, KB, V0, V1)                                          \
        {                                                                     \
            __builtin_amdgcn_s_setprio(1);                                    \
            _Pragma("unroll")                                                 \
            for (int j = 0; j < NJ; ++j) {                                    \
                if (wv + 4 * j < 25) {                                        \
                    const f32x4 sA = __builtin_amdgcn_mfma_f32_16x16x32_bf16(KA, qf[j], CUR[j][0], 0, 0, 0); \
                    const f32x4 sB = __builtin_amdgcn_mfma_f32_16x16x32_bf16(KB, qf[j], CUR[j][1], 0, 0, 0); \
                    union { unsigned u[4]; bf16x8 v; } pw;                    \
                    pw.u[0] = pkbf(exp2_hw(sA[0]), exp2_hw(sA[1]));           \
                    pw.u[1] = pkbf(exp2_hw(sA[2]), exp2_hw(sA[3]));           \
                    pw.u[2] = pkbf(exp2_hw(sB[0]), exp2_hw(sB[1]));           \
                    pw.u[3] = pkbf(exp2_hw(sB[2]), exp2_hw(sB[3]));           \
                    o0[j]   = __builtin_amdgcn_mfma_f32_16x16x32_bf16(V0, pw.v, o0[j], 0, 0, 0);   \
                    o1[j]   = __builtin_amdgcn_mfma_f32_16x16x32_bf16(V1, pw.v, o1[j], 0, 0, 0);   \
                    sumv[j] = __builtin_amdgcn_mfma_f32_16x16x32_bf16(onesf, pw.v, sumv[j], 0, 0, 0); \
                }                                                             \
            }                                                                 \
            __builtin_amdgcn_s_setprio(0);                                    \
        }

        // prologue: stage 0 = ch 0
        CH_PREB(0, bufA)
        CH_PREF(0, kA0, kB0, v00, v10)

#pragma unroll 1
        for (int chp = 0; chp < 12; chp += 2) {
            CH_PREF(chp + 1, kA1, kB1, v01, v11)
            CH_PREB(chp + 1, bufB)
            CH_BODY(bufA, kA0, kB0, v00, v10)
            CH_PREF(chp + 2, kA0, kB0, v00, v10)
            CH_PREB(chp + 2, bufA)
            CH_BODY(bufB, kA1, kB1, v01, v11)
        }
        CH_BODY(bufA, kA0, kB0, v00, v10)
#undef CH_BODY
#undef CH_PREB
#undef CH_PREF

#pragma unroll
        for (int j = 0; j < NJ; ++j) {
            const int mt   = wv + 4 * j;
            const int qtok = mt * 16 + l16;
            if (mt < 25) {
                const float inv = 1.0f / sumv[j][0];   // all 4 rows identical
                if (qtok < VOL) {
                    bf16x4 w0, w1;
#pragma unroll
                    for (int r = 0; r < 4; ++r) {
                        w0[r] = (bf16)(o0[j][r] * inv);
                        w1[r] = (bf16)(o1[j][r] * inv);
                    }
                    bf16* op = aw + ((size_t)win * VPAD + qtok) * DIMC + head * HD + lg * 4;
                    *(bf16x4*)op = w0;
                    *(bf16x4*)(op + 16) = w1;
                }
            }
        }
    }
}

// ---------------------------------------------------------------------------
// Kernel B: proj GEMM (bf16 W) + inverse-shift scatter; 512 blocks
// ---------------------------------------------------------------------------
__global__ __launch_bounds__(256, 2) void swin_proj(
    const bf16* __restrict__ aw, const bf16* __restrict__ wpb,
    const float* __restrict__ bproj, float* __restrict__ out)
{
    const int bid  = blockIdx.x;           // 0..511
    const int xcd  = bid & 7;
    const int rest = bid >> 3;             // 0..63
    const int win  = xcd * 32 + (rest & 31);
    const int half = rest >> 5;            // 0..1
    const int b    = win >> 7;
    const int wrem = win & 127;
    const int it   = wrem >> 6;
    const int ih   = (wrem >> 3) & 7;
    const int iw   = wrem & 7;

    const int tid  = threadIdx.x;
    const int lane = tid & 63;
    const int wid  = tid >> 6;
    const int l16  = lane & 15;
    const int lg   = lane >> 4;

    const int mt_end = half ? 25 : 13;
    for (int mt = 13 * half + wid; mt < mt_end; mt += 4) {
        bf16x8 af[4];
        const bf16* ap = aw + ((size_t)win * VPAD + mt * 16 + l16) * DIMC + 8 * lg;
#pragma unroll
        for (int ks = 0; ks < 4; ++ks) af[ks] = *(const bf16x8*)(ap + ks * 32);

        float* ob[4]; bool qok[4];
#pragma unroll
        for (int r = 0; r < 4; ++r) {
            int q = mt * 16 + lg * 4 + r;
            qok[r] = q < VOL; if (!qok[r]) q = 0;
            const int lt = q / 49, rr = q - lt * 49;
            const int lh = rr / 7, lw = rr - lh * 7;
            const int t0 = (it * 8 + lt + 4) & 15;
            int h0 = ih * 7 + lh + 3; if (h0 >= 56) h0 -= 56;
            int w0 = iw * 7 + lw + 3; if (w0 >= 56) w0 -= 56;
            ob[r] = out + (size_t)(((b * 16 + t0) * 56 + h0) * 56 + w0) * DIMC;
        }
#pragma unroll
        for (int nt = 0; nt < 8; ++nt) {
            f32x4 acc = {0.f, 0.f, 0.f, 0.f};
            const bf16* wp = wpb + (size_t)(nt * 16 + l16) * DIMC + 8 * lg;
#pragma unroll
            for (int ks = 0; ks < 4; ++ks)
                acc = __builtin_amdgcn_mfma_f32_16x16x32_bf16(af[ks], *(const bf16x8*)(wp + ks * 32), acc, 0, 0, 0);
            const float bv = bproj[nt * 16 + l16];
#pragma unroll
            for (int r = 0; r < 4; ++r)
                if (qok[r]) ob[r][nt * 16 + l16] = acc[r] + bv;
        }
    }
}

extern "C" void kernel_launch(void* const* d_in, const int* in_sizes, int n_in,
                              void* d_out, int out_size, void* d_ws, size_t ws_size,
                              hipStream_t stream) {
    const float* x     = (const float*)d_in[0];
    const float* wqkv  = (const float*)d_in[1];
    const float* bqkv  = (const float*)d_in[2];
    const float* wproj = (const float*)d_in[3];
    const float* bproj = (const float*)d_in[4];
    const float* btab  = (const float*)d_in[5];
    bf16*  aw  = (bf16*)d_ws;                                          // 27.26 MB
    float* tbl = (float*)((char*)d_ws + AW_BYTES);                     // 21.30 MB
    bf16*  wpb = (bf16*)((char*)d_ws + AW_BYTES + TBLF_BYTES);         // 32 KB
    float* out = (float*)d_out;

    const int tbl_threads = 8 * HEADS * TQ * (TK / 4);
    gen_table<<<dim3((tbl_threads + 255) / 256), dim3(256), 0, stream>>>(btab, tbl, wproj, wpb);
    swin_attn<<<dim3(1024), dim3(256), 0, stream>>>(x, wqkv, bqkv, tbl, aw);
    swin_proj<<<dim3(512), dim3(256), 0, stream>>>(aw, wpb, bproj, out);
}

// Round 23
// 114.919 us; speedup vs baseline: 1.9920x; 1.9920x over previous
//
#include <hip/hip_runtime.h>

// ---------------------------------------------------------------------------
// Swin-3D shifted window attention, MI355X (gfx950)
// R23 = R21 champion (115.0us), reverted after R22 falsified the clamp-break
//      theory (f32 bias table -> spill at the absolute 128-VGPR clamp).
//      Final configuration:
//      - Kernel A (attn): per (window,head), 256 thr, static 51.7KB LDS,
//        waves_per_eu(2,2); QKV on MFMA with hoisted W frags; Q captured to
//        regs during phase 1 (tile ownership identical across phases), K
//        overwrites Q's LDS rows, V^T swizzled; one __syncthreads.
//        Phase 2: ch-outer/q-inner register-P interleaved S^T tiles,
//        no-max softmax in exp2 domain, softmax denominator via
//        mfma(ones,P) on the matrix pipe, s_setprio around compute,
//        bias(bf16)+K/V-frag double buffers, x-load double buffer in ph1.
//      - Kernel B (proj): bf16 W, MFMA, inverse-shift scatter.
//      - gen_table: bias+mask (8 patterns) pre-scaled by log2e + wproj
//        f32->bf16, merged into one launch.
// ---------------------------------------------------------------------------

#define DIMC   128
#define HEADS  4
#define HD     32
#define VOL    392
#define VPAD   416
#define TQ     400
#define TK     416
#define SCALE2 0.25503490443f          // (1/sqrt(32)) * log2(e)
#define LOG2E  1.4426950408889634f
#define MASK2  144.26950408889634f     // 100 * log2(e)

typedef __bf16 bf16;
typedef __attribute__((ext_vector_type(8))) __bf16 bf16x8;
typedef __attribute__((ext_vector_type(4))) __bf16 bf16x4;
typedef __attribute__((ext_vector_type(2))) __bf16 bf16x2;
typedef __attribute__((ext_vector_type(4))) float  f32x4;

// LDS layout (bf16 elements): R0 = K (Q transiently), R1 = V^T
#define OFF_VT  (392*32)
#define VTCOLS  416
#define LDS_ELEMS (392*32 + 32*VTCOLS)       // 25856 elems = 51712 B
#define AW_BYTES  (256ull * VPAD * DIMC * 2ull)          // 27.26 MB
#define TBL_BYTES (8ull * HEADS * TQ * TK * 2ull)        // 10.65 MB

static __device__ inline bf16x8 pack8(float4 a, float4 b) {
    bf16x8 r;
    r[0] = (bf16)a.x; r[1] = (bf16)a.y; r[2] = (bf16)a.z; r[3] = (bf16)a.w;
    r[4] = (bf16)b.x; r[5] = (bf16)b.y; r[6] = (bf16)b.z; r[7] = (bf16)b.w;
    return r;
}
static __device__ inline bf16x8 zero8() {
    bf16x8 z;
#pragma unroll
    for (int i = 0; i < 8; ++i) z[i] = (bf16)0.0f;
    return z;
}
static __device__ inline bf16x8 ones8() {
    bf16x8 z;
#pragma unroll
    for (int i = 0; i < 8; ++i) z[i] = (bf16)1.0f;
    return z;
}
static __device__ inline int swz4(int row) { return ((row >> 1) ^ (row >> 3)) & 3; }

static __device__ inline unsigned pkbf(float a, float b) {
    bf16x2 t; t[0] = (bf16)a; t[1] = (bf16)b;
    return __builtin_bit_cast(unsigned, t);
}

#if defined(__has_builtin)
#if __has_builtin(__builtin_amdgcn_exp2f)
#define HAS_EXP2 1
#endif
#endif
static __device__ inline float exp2_hw(float x) {
#ifdef HAS_EXP2
    return __builtin_amdgcn_exp2f(x);
#else
    float r; asm volatile("v_exp_f32 %0, %1\n\ts_nop 0" : "=v"(r) : "v"(x)); return r;
#endif
}

// ---------------------------------------------------------------------------
// bias+mask table (pre-scaled by log2e) + wproj f32->bf16 conversion (merged)
// ---------------------------------------------------------------------------
__global__ __launch_bounds__(256) void gen_table(const float* __restrict__ btab,
                                                 bf16* __restrict__ tbl,
                                                 const float* __restrict__ wproj,
                                                 bf16* __restrict__ wpb) {
    const int idx = blockIdx.x * 256 + threadIdx.x;
    // merged: wproj conversion on the first 4096 threads
    if (idx < DIMC * DIMC / 4) {
        const int i = idx * 4;
        float4 u = *(const float4*)(wproj + i);
        bf16x4 o; o[0] = (bf16)u.x; o[1] = (bf16)u.y; o[2] = (bf16)u.z; o[3] = (bf16)u.w;
        *(bf16x4*)(wpb + i) = o;
    }
    const int total = 8 * HEADS * TQ * (TK / 4);
    if (idx >= total) return;
    const int k4  = (idx % (TK / 4)) * 4;
    const int q   = (idx / (TK / 4)) % TQ;
    const int h   = (idx / ((TK / 4) * TQ)) & 3;
    const int pat = idx / ((TK / 4) * TQ * HEADS);
    const int tb = (pat >> 2) & 1, hb = (pat >> 1) & 1, wb = pat & 1;

    int qt = 0, qh = 0, qw = 0, lq = 0;
    if (q < VOL) {
        qt = q / 49; const int qr = q - qt * 49; qh = qr / 7; qw = qr - qh * 7;
        lq = (tb ? (qt < 4 ? 1 : 2) : 0) * 9 + (hb ? (qh < 4 ? 1 : 2) : 0) * 3 +
             (wb ? (qw < 4 ? 1 : 2) : 0);
    }
    bf16x4 out;
#pragma unroll
    for (int j = 0; j < 4; ++j) {
        const int k = k4 + j;
        float v;
        if (k >= VOL)      v = -30000.0f;
        else if (q >= VOL) v = 0.0f;
        else {
            const int kt = k / 49; const int kr = k - kt * 49;
            const int kh = kr / 7; const int kw = kr - kh * 7;
            const int rel = ((qt - kt + 7) * 13 + (qh - kh + 6)) * 13 + (qw - kw + 6);
            v = btab[rel * HEADS + h] * LOG2E;
            const int lk = (tb ? (kt < 4 ? 1 : 2) : 0) * 9 +
                           (hb ? (kh < 4 ? 1 : 2) : 0) * 3 +
                           (wb ? (kw < 4 ? 1 : 2) : 0);
            if (lq != lk) v -= MASK2;
        }
        out[j] = (bf16)v;
    }
    *(bf16x4*)&tbl[((size_t)(pat * HEADS + h) * TQ + q) * TK + k4] = out;
}

// ---------------------------------------------------------------------------
// Kernel A: per (window,head), 256 threads / 4 waves, static 51.7KB LDS.
// ---------------------------------------------------------------------------
#define NJ 7   // q-tiles per wave: wave wv owns mt = wv + 4j

__global__ __attribute__((amdgpu_flat_work_group_size(256, 256),
                          amdgpu_waves_per_eu(2, 2)))
void swin_attn(
    const float* __restrict__ x, const float* __restrict__ wqkv,
    const float* __restrict__ bqkv, const bf16* __restrict__ tbl,
    bf16* __restrict__ aw)
{
    __shared__ __align__(16) bf16 lds[LDS_ELEMS];

    // XCD-aware mapping: 4 heads of a window -> same XCD (bid%8)
    const int bid  = blockIdx.x;
    const int xcd  = bid & 7;
    const int tt   = bid >> 3;             // 0..127
    const int win  = xcd * 32 + (tt >> 2); // 0..255
    const int head = tt & 3;
    const int b    = win >> 7;
    const int wrem = win & 127;
    const int it   = wrem >> 6;
    const int ih   = (wrem >> 3) & 7;
    const int iw   = wrem & 7;
    const int pat  = ((it == 1) ? 4 : 0) | ((ih == 7) ? 2 : 0) | ((iw == 7) ? 1 : 0);

    const int tid  = threadIdx.x;
    const int lane = tid & 63;
    const int wv   = tid >> 6;             // wave 0..3
    const int l16  = lane & 15;
    const int lg   = lane >> 4;

    const bf16* tblh = tbl + (size_t)(pat * HEADS + head) * (TQ * TK);

    // ---- hoisted W fragments: o = g*2+h2, g: 0=Q 1=K 2=V ----
    bf16x8 wfr[6][4];
    float  bcol[4];
#pragma unroll
    for (int o = 0; o < 6; ++o) {
        const int g = o >> 1, h2 = o & 1;
        const int wrow = g * DIMC + head * HD + h2 * 16 + l16;
        const float* wp = wqkv + (size_t)wrow * DIMC + 8 * lg;
#pragma unroll
        for (int ks = 0; ks < 4; ++ks)
            wfr[o][ks] = pack8(*(const float4*)(wp + ks * 32),
                               *(const float4*)(wp + ks * 32 + 4));
        if (o < 4) bcol[o] = bqkv[wrow];
    }
    float bvr[2][4];
#pragma unroll
    for (int h2 = 0; h2 < 2; ++h2)
#pragma unroll
        for (int r = 0; r < 4; ++r)
            bvr[h2][r] = bqkv[2 * DIMC + head * HD + h2 * 16 + lg * 4 + r];

    bf16x8 qf[NJ];                 // per-wave Q fragments (STATIC indexing)
#pragma unroll
    for (int j = 0; j < NJ; ++j) qf[j] = zero8();

    // ------- phase 1 (j unrolled, x loads double-buffered one tile ahead) --
    // raw prefetch: 8 float4 per tile; pairs (u>>1)*32 + (u&1)*4 floats.
    float4 xr0[8], xr1[8];
    bool   ok0 = false, ok1 = false;

#define P1_LOAD(MT, XR, OK)                                                   \
    {                                                                         \
        const int mt_ = (MT);                                                 \
        const int tv_ = mt_ * 16 + l16;                                       \
        OK = (mt_ < 26) && (tv_ < VOL);                                       \
        if (OK) {                                                             \
            const int lt_ = tv_ / 49, rr_ = tv_ - lt_ * 49;                   \
            const int lh_ = rr_ / 7, lw_ = rr_ - lh_ * 7;                     \
            const int t0_ = (it * 8 + lt_ + 4) & 15;                          \
            int h0_ = ih * 7 + lh_ + 3; if (h0_ >= 56) h0_ -= 56;             \
            int w0_ = iw * 7 + lw_ + 3; if (w0_ >= 56) w0_ -= 56;             \
            const float* xp_ = x + (size_t)(((b * 16 + t0_) * 56 + h0_) * 56 + w0_) * DIMC + 8 * lg; \
            _Pragma("unroll")                                                 \
            for (int u = 0; u < 8; ++u)                                       \
                XR[u] = *(const float4*)(xp_ + (u >> 1) * 32 + (u & 1) * 4);  \
        }                                                                     \
    }
#define P1_BODY(J, XR, OK)                                                    \
    {                                                                         \
        const int mt = wv + 4 * (J);                                          \
        if (mt < 26) {                                                        \
            const int tv = mt * 16 + l16;                                     \
            bf16x8 af[4];                                                     \
            _Pragma("unroll")                                                 \
            for (int ks = 0; ks < 4; ++ks)                                    \
                af[ks] = OK ? pack8(XR[2 * ks], XR[2 * ks + 1]) : zero8();    \
            _Pragma("unroll")                                                 \
            for (int o = 0; o < 2; ++o) {                                     \
                f32x4 acc = {0.f, 0.f, 0.f, 0.f};                             \
                _Pragma("unroll")                                             \
                for (int ks = 0; ks < 4; ++ks)                                \
                    acc = __builtin_amdgcn_mfma_f32_16x16x32_bf16(af[ks], wfr[o][ks], acc, 0, 0, 0); \
                const int cb = (o & 1) * 16 + l16;                            \
                _Pragma("unroll")                                             \
                for (int r = 0; r < 4; ++r) {                                 \
                    const int row = mt * 16 + lg * 4 + r;                     \
                    if (row < VOL)                                            \
                        lds[row * 32 + (cb ^ (swz4(row) << 3))] = (bf16)((acc[r] + bcol[o]) * SCALE2); \
                }                                                             \
            }                                                                 \
            if (mt < 25) {                                                    \
                const int qr = (tv < VOL) ? tv : (VOL - 1);                   \
                qf[(J)] = *(const bf16x8*)&lds[qr * 32 + ((lg * 8) ^ (swz4(qr) << 3))]; \
            }                                                                 \
            _Pragma("unroll")                                                 \
            for (int o = 2; o < 4; ++o) {                                     \
                f32x4 acc = {0.f, 0.f, 0.f, 0.f};                             \
                _Pragma("unroll")                                             \
                for (int ks = 0; ks < 4; ++ks)                                \
                    acc = __builtin_amdgcn_mfma_f32_16x16x32_bf16(af[ks], wfr[o][ks], acc, 0, 0, 0); \
                const int cb = (o & 1) * 16 + l16;                            \
                _Pragma("unroll")                                             \
                for (int r = 0; r < 4; ++r) {                                 \
                    const int row = mt * 16 + lg * 4 + r;                     \
                    if (row < VOL)                                            \
                        lds[row * 32 + (cb ^ (swz4(row) << 3))] = (bf16)(acc[r] + bcol[o]); \
                }                                                             \
            }                                                                 \
            _Pragma("unroll")                                                 \
            for (int h2 = 0; h2 < 2; ++h2) {                                  \
                f32x4 acc = {0.f, 0.f, 0.f, 0.f};                             \
                _Pragma("unroll")                                             \
                for (int ks = 0; ks < 4; ++ks)                                \
                    acc = __builtin_amdgcn_mfma_f32_16x16x32_bf16(wfr[4 + h2][ks], af[ks], acc, 0, 0, 0); \
                _Pragma("unroll")                                             \
                for (int r = 0; r < 4; ++r) {                                 \
                    const int n = h2 * 16 + lg * 4 + r;                       \
                    lds[OFF_VT + n * VTCOLS + (tv ^ (swz4(n) << 3))] = (bf16)(acc[r] + bvr[h2][r]); \
                }                                                             \
            }                                                                 \
        }                                                                     \
    }

    P1_LOAD(wv, xr0, ok0)
    P1_LOAD(wv + 4, xr1, ok1)
    P1_BODY(0, xr0, ok0)
    P1_LOAD(wv + 8, xr0, ok0)
    P1_BODY(1, xr1, ok1)
    P1_LOAD(wv + 12, xr1, ok1)
    P1_BODY(2, xr0, ok0)
    P1_LOAD(wv + 16, xr0, ok0)
    P1_BODY(3, xr1, ok1)
    P1_LOAD(wv + 20, xr1, ok1)
    P1_BODY(4, xr0, ok0)
    P1_LOAD(wv + 24, xr0, ok0)
    P1_BODY(5, xr1, ok1)
    P1_BODY(6, xr0, ok0)
#undef P1_LOAD
#undef P1_BODY
    __syncthreads();

    // ---------------- phase 2: ch-outer / q-inner, no-max softmax --------
    // Interleaved S^T tiles: tile A keys = 32ch+{0-3,8-11,16-19,24-27},
    // tile B = +4. Lane (l16,lg): sA[r]=P(key 32ch+8lg+r), sB[r]=+4 -> PV
    // B-frag directly. K reads for keys>=392 overrun into initialized V^T.
    // Denominator on the MFMA pipe: sumv[j] = mfma(ones, P, sumv[j]).
    // Bias rows and K/V LDS fragments double-buffered one ch ahead.
    {
        const int c = l16 & 3, d = l16 >> 2;
        const int rowA  = c + 8 * d;
        const int swzA  = (c >> 1) ^ d;
        const int swzB  = (2 + (c >> 1)) ^ d;
        const int kbA   = rowA * 32       + ((lg * 8) ^ (swzA << 3));
        const int kbB   = (rowA + 4) * 32 + ((lg * 8) ^ (swzB << 3));
        const int vb0   = OFF_VT + l16 * VTCOLS        + ((lg * 8) ^ (swz4(l16) << 3));
        const int vb1   = OFF_VT + (16 + l16) * VTCOLS + ((lg * 8) ^ (swz4(16 + l16) << 3));
        const bf16x8 onesf = ones8();

        int    tbOff[NJ];              // 32-bit byte offsets into tblh
        f32x4  o0[NJ], o1[NJ], sumv[NJ];
#pragma unroll
        for (int j = 0; j < NJ; ++j) {
            const int qtok = (wv + 4 * j) * 16 + l16;
            const int qc   = (qtok < TQ) ? qtok : (TQ - 1);
            tbOff[j] = (qc * TK + 8 * lg) * 2;
            o0[j]   = f32x4{0.f, 0.f, 0.f, 0.f};
            o1[j]   = f32x4{0.f, 0.f, 0.f, 0.f};
            sumv[j] = f32x4{0.f, 0.f, 0.f, 0.f};
        }

        uint4 bufA[NJ], bufB[NJ];
        bf16x8 kA0, kB0, v00, v10, kA1, kB1, v01, v11;

#define CH_PREB(CH, DST)                                                      \
        {                                                                     \
            const int chp_ = (CH) < 12 ? (CH) : 12;                           \
            _Pragma("unroll")                                                 \
            for (int j = 0; j < NJ; ++j)                                      \
                DST[j] = *(const uint4*)((const char*)tblh + tbOff[j] + chp_ * 64); \
        }
#define CH_PREF(CH, KA, KB, V0, V1)                                           \
        {                                                                     \
            const int chf_ = (CH) < 12 ? (CH) : 12;                           \
            KA = *(const bf16x8*)&lds[kbA + chf_ * 1024];                     \
            KB = *(const bf16x8*)&lds[kbB + chf_ * 1024];                     \
            V0 = *(const bf16x8*)&lds[vb0 + chf_ * 32];                       \
            V1 = *(const bf16x8*)&lds[vb1 + chf_ * 32];                       \
        }
#define CH_BODY(CUR, KA, KB, V0, V1)                                          \
        {                                                                     \
            __builtin_amdgcn_s_setprio(1);                                    \
            _Pragma("unroll")                                                 \
            for (int j = 0; j < NJ; ++j) {                                    \
                if (wv + 4 * j < 25) {                                        \
                    const uint4 bu = CUR[j];                                  \
                    f32x4 cA, cB;                                             \
                    cA[0] = __builtin_bit_cast(float, bu.x << 16);            \
                    cA[1] = __builtin_bit_cast(float, bu.x & 0xffff0000u);    \
                    cA[2] = __builtin_bit_cast(float, bu.y << 16);            \
                    cA[3] = __builtin_bit_cast(float, bu.y & 0xffff0000u);    \
                    cB[0] = __builtin_bit_cast(float, bu.z << 16);            \
                    cB[1] = __builtin_bit_cast(float, bu.z & 0xffff0000u);    \
                    cB[2] = __builtin_bit_cast(float, bu.w << 16);            \
                    cB[3] = __builtin_bit_cast(float, bu.w & 0xffff0000u);    \
                    const f32x4 sA = __builtin_amdgcn_mfma_f32_16x16x32_bf16(KA, qf[j], cA, 0, 0, 0); \
                    const f32x4 sB = __builtin_amdgcn_mfma_f32_16x16x32_bf16(KB, qf[j], cB, 0, 0, 0); \
                    union { unsigned u[4]; bf16x8 v; } pw;                    \
                    pw.u[0] = pkbf(exp2_hw(sA[0]), exp2_hw(sA[1]));           \
                    pw.u[1] = pkbf(exp2_hw(sA[2]), exp2_hw(sA[3]));           \
                    pw.u[2] = pkbf(exp2_hw(sB[0]), exp2_hw(sB[1]));           \
                    pw.u[3] = pkbf(exp2_hw(sB[2]), exp2_hw(sB[3]));           \
                    o0[j]   = __builtin_amdgcn_mfma_f32_16x16x32_bf16(V0, pw.v, o0[j], 0, 0, 0);   \
                    o1[j]   = __builtin_amdgcn_mfma_f32_16x16x32_bf16(V1, pw.v, o1[j], 0, 0, 0);   \
                    sumv[j] = __builtin_amdgcn_mfma_f32_16x16x32_bf16(onesf, pw.v, sumv[j], 0, 0, 0); \
                }                                                             \
            }                                                                 \
            __builtin_amdgcn_s_setprio(0);                                    \
        }

        // prologue: stage 0 = ch 0
        CH_PREB(0, bufA)
        CH_PREF(0, kA0, kB0, v00, v10)

#pragma unroll 1
        for (int chp = 0; chp < 12; chp += 2) {
            CH_PREF(chp + 1, kA1, kB1, v01, v11)
            CH_PREB(chp + 1, bufB)
            CH_BODY(bufA, kA0, kB0, v00, v10)
            CH_PREF(chp + 2, kA0, kB0, v00, v10)
            CH_PREB(chp + 2, bufA)
            CH_BODY(bufB, kA1, kB1, v01, v11)
        }
        CH_BODY(bufA, kA0, kB0, v00, v10)
#undef CH_BODY
#undef CH_PREB
#undef CH_PREF

#pragma unroll
        for (int j = 0; j < NJ; ++j) {
            const int mt   = wv + 4 * j;
            const int qtok = mt * 16 + l16;
            if (mt < 25) {
                const float inv = 1.0f / sumv[j][0];   // all 4 rows identical
                if (qtok < VOL) {
                    bf16x4 w0, w1;
#pragma unroll
                    for (int r = 0; r < 4; ++r) {
                        w0[r] = (bf16)(o0[j][r] * inv);
                        w1[r] = (bf16)(o1[j][r] * inv);
                    }
                    bf16* op = aw + ((size_t)win * VPAD + qtok) * DIMC + head * HD + lg * 4;
                    *(bf16x4*)op = w0;
                    *(bf16x4*)(op + 16) = w1;
                }
            }
        }
    }
}

// ---------------------------------------------------------------------------
// Kernel B: proj GEMM (bf16 W) + inverse-shift scatter; 512 blocks
// ---------------------------------------------------------------------------
__global__ __launch_bounds__(256, 2) void swin_proj(
    const bf16* __restrict__ aw, const bf16* __restrict__ wpb,
    const float* __restrict__ bproj, float* __restrict__ out)
{
    const int bid  = blockIdx.x;           // 0..511
    const int xcd  = bid & 7;
    const int rest = bid >> 3;             // 0..63
    const int win  = xcd * 32 + (rest & 31);
    const int half = rest >> 5;            // 0..1
    const int b    = win >> 7;
    const int wrem = win & 127;
    const int it   = wrem >> 6;
    const int ih   = (wrem >> 3) & 7;
    const int iw   = wrem & 7;

    const int tid  = threadIdx.x;
    const int lane = tid & 63;
    const int wid  = tid >> 6;
    const int l16  = lane & 15;
    const int lg   = lane >> 4;

    const int mt_end = half ? 25 : 13;
    for (int mt = 13 * half + wid; mt < mt_end; mt += 4) {
        bf16x8 af[4];
        const bf16* ap = aw + ((size_t)win * VPAD + mt * 16 + l16) * DIMC + 8 * lg;
#pragma unroll
        for (int ks = 0; ks < 4; ++ks) af[ks] = *(const bf16x8*)(ap + ks * 32);

        float* ob[4]; bool qok[4];
#pragma unroll
        for (int r = 0; r < 4; ++r) {
            int q = mt * 16 + lg * 4 + r;
            qok[r] = q < VOL; if (!qok[r]) q = 0;
            const int lt = q / 49, rr = q - lt * 49;
            const int lh = rr / 7, lw = rr - lh * 7;
            const int t0 = (it * 8 + lt + 4) & 15;
            int h0 = ih * 7 + lh + 3; if (h0 >= 56) h0 -= 56;
            int w0 = iw * 7 + lw + 3; if (w0 >= 56) w0 -= 56;
            ob[r] = out + (size_t)(((b * 16 + t0) * 56 + h0) * 56 + w0) * DIMC;
        }
#pragma unroll
        for (int nt = 0; nt < 8; ++nt) {
            f32x4 acc = {0.f, 0.f, 0.f, 0.f};
            const bf16* wp = wpb + (size_t)(nt * 16 + l16) * DIMC + 8 * lg;
#pragma unroll
            for (int ks = 0; ks < 4; ++ks)
                acc = __builtin_amdgcn_mfma_f32_16x16x32_bf16(af[ks], *(const bf16x8*)(wp + ks * 32), acc, 0, 0, 0);
            const float bv = bproj[nt * 16 + l16];
#pragma unroll
            for (int r = 0; r < 4; ++r)
                if (qok[r]) ob[r][nt * 16 + l16] = acc[r] + bv;
        }
    }
}

extern "C" void kernel_launch(void* const* d_in, const int* in_sizes, int n_in,
                              void* d_out, int out_size, void* d_ws, size_t ws_size,
                              hipStream_t stream) {
    const float* x     = (const float*)d_in[0];
    const float* wqkv  = (const float*)d_in[1];
    const float* bqkv  = (const float*)d_in[2];
    const float* wproj = (const float*)d_in[3];
    const float* bproj = (const float*)d_in[4];
    const float* btab  = (const float*)d_in[5];
    bf16*  aw  = (bf16*)d_ws;                                          // 27.26 MB
    bf16*  tbl = (bf16*)((char*)d_ws + AW_BYTES);                      // 10.65 MB
    bf16*  wpb = (bf16*)((char*)d_ws + AW_BYTES + TBL_BYTES);          // 32 KB
    float* out = (float*)d_out;

    const int tbl_threads = 8 * HEADS * TQ * (TK / 4);
    gen_table<<<dim3((tbl_threads + 255) / 256), dim3(256), 0, stream>>>(btab, tbl, wproj, wpb);
    swin_attn<<<dim3(1024), dim3(256), 0, stream>>>(x, wqkv, bqkv, tbl, aw);
    swin_proj<<<dim3(512), dim3(256), 0, stream>>>(aw, wpb, bproj, out);
}